// Round 5
// baseline (165.636 us; speedup 1.0000x reference)
//
#include <hip/hip_runtime.h>
#include <hip/hip_bf16.h>

typedef unsigned short u16;
typedef unsigned int u32;
typedef __bf16 bf16x8 __attribute__((ext_vector_type(8)));
typedef float f32x4 __attribute__((ext_vector_type(4)));

#define LDA 136   // 128+8 bf16 pad: row stride 272B = 16B-aligned, non-pow2 banks

__device__ __forceinline__ u16 f2b(float f) {
  __bf16 b = (__bf16)f;
  return __builtin_bit_cast(u16, b);
}
__device__ __forceinline__ float b2f(u16 h) {
  u32 u = ((u32)h) << 16;
  return __builtin_bit_cast(float, u);
}
__device__ __forceinline__ u32 pk2(float lo, float hi) {
  return (u32)f2b(lo) | ((u32)f2b(hi) << 16);
}
__device__ __forceinline__ bf16x8 zero8() {
  union { int4 i; bf16x8 v; } u;
  u.i = make_int4(0, 0, 0, 0);
  return u.v;
}
__device__ __forceinline__ f32x4 mfma16(bf16x8 a, bf16x8 b, f32x4 c) {
  return __builtin_amdgcn_mfma_f32_16x16x32_bf16(a, b, c, 0, 0, 0);
}
__device__ __forceinline__ ushort4 pk4(float a, float b, float c, float d) {
  ushort4 r; r.x = f2b(a); r.y = f2b(b); r.z = f2b(c); r.w = f2b(d);
  return r;
}

// Transpose C-layout frag pair {ve=tile 2kk, vo=tile 2kk+1} (row-index -> k):
// output lane(l15,lg) element j = M[row=kk*32+lg*8+j][col=l15].
// Verified R3/R4 (P^T gather and av build passed absmax).
__device__ __forceinline__ bf16x8 gatherB(const f32x4& ve, const f32x4& vo,
                                          bool odd_valid, float scale,
                                          int l15, int lg) {
  u32 pe0 = pk2(ve[0] * scale, ve[1] * scale);
  u32 pe1 = pk2(ve[2] * scale, ve[3] * scale);
  u32 po0 = 0, po1 = 0;
  if (odd_valid) {
    po0 = pk2(vo[0] * scale, vo[1] * scale);
    po1 = pk2(vo[2] * scale, vo[3] * scale);
  }
  int s0 = ((lg & 1) * 2) * 16 + l15;
  u32 a0 = __shfl(pe0, s0),      a1 = __shfl(pe1, s0);
  u32 a2 = __shfl(pe0, s0 + 16), a3 = __shfl(pe1, s0 + 16);
  u32 b0 = __shfl(po0, s0),      b1 = __shfl(po1, s0);
  u32 b2 = __shfl(po0, s0 + 16), b3 = __shfl(po1, s0 + 16);
  union { u32 u[4]; bf16x8 v; } fr;
  bool lo = (lg < 2);
  fr.u[0] = lo ? a0 : b0; fr.u[1] = lo ? a1 : b1;
  fr.u[2] = lo ? a2 : b2; fr.u[3] = lo ? a3 : b3;
  return fr.v;
}

// ---------------- weight prep ----------------
// ws (u16): WqT[128][128]@0 (WqT[h*16+e][d]=Wq[h][d][e]), WkT@16384, WvT@32768,
//           WoT@49152 (WoT[n][k]=Wo[k][n]), W1T[512][128]@65536 (W1T[n][k]=W1[k][n]),
//           W2T2[128][512]@131072 (W2T2[c][n]=W2[n][c])
__global__ void prep_kernel(const float* __restrict__ Wq, const float* __restrict__ Wk,
                            const float* __restrict__ Wv, const float* __restrict__ Wo,
                            const float* __restrict__ W1, const float* __restrict__ W2,
                            u16* __restrict__ o) {
  int i = blockIdx.x * 256 + threadIdx.x;
  if (i >= 196608) return;
  float v;
  if (i < 49152) {
    int which = i >> 14, j = i & 16383;
    int n = j >> 7, k = j & 127;
    const float* W = (which == 0) ? Wq : (which == 1) ? Wk : Wv;
    v = W[((n >> 4) * 128 + k) * 16 + (n & 15)];
  } else if (i < 65536) {
    int j = i - 49152;
    v = Wo[(j & 127) * 128 + (j >> 7)];
  } else if (i < 131072) {
    int j = i - 65536;
    v = W1[(j & 127) * 512 + (j >> 7)];
  } else {
    int j = i - 131072;
    int c = j >> 9, n = j & 511;
    v = W2[n * 128 + c];
  }
  o[i] = f2b(v);
}

// ---------------- fused transformer block ----------------
// 8 waves, 2 LDS buffers (69.6 KB -> 2 blocks/CU). Weights ride the MFMA A-slot
// (swapped orientation) so activation stores are packed ushort4 and residual
// global I/O is float4. Attention is fully wave-private (wave w = head w).
__global__ void __launch_bounds__(512, 4)
tblock_kernel(const float* __restrict__ xg, const u16* __restrict__ wts,
              const float* __restrict__ bo, const float* __restrict__ b1,
              const float* __restrict__ b2, const float* __restrict__ g1,
              const float* __restrict__ be1, const float* __restrict__ g2,
              const float* __restrict__ be2, float* __restrict__ out) {
  extern __shared__ u16 sm[];
  u16* buf1 = sm;                // h -> x1(bf16) -> h2(in-place)
  u16* buf2 = sm + 128 * LDA;    // K -> Q -> O(in-place) -> relu chunks

  const int tid  = threadIdx.x;
  const int w    = tid >> 6;
  const int lane = tid & 63;
  const int l15  = lane & 15;
  const int lg   = lane >> 4;
  const int mr   = w >> 2;           // FFN/Wo: row half 0/1 (64 rows)
  const int nc   = w & 3;            // FFN/Wo: col group (32 cols)
  const int tr0  = mr * 64;
  const int cb   = nc * 32;

  const u16* WqT  = wts;
  const u16* WkT  = wts + 16384;
  const u16* WvT  = wts + 32768;
  const u16* WoT  = wts + 49152;
  const u16* W1T  = wts + 65536;
  const u16* W2T2 = wts + 131072;

  const float* xp = xg + (size_t)blockIdx.x * 16384;
  float*       op = out + (size_t)blockIdx.x * 16384;

  const f32x4 zf4 = {0.f, 0.f, 0.f, 0.f};
  const bf16x8 zb8 = zero8();

  // ---- LN1 (transposed-reg): wave w owns rows w*16..+15; float4 x loads
  {
    const int t = w * 16 + l15;
    float v[8][4];
    #pragma unroll
    for (int nt = 0; nt < 8; ++nt) {
      float4 f = *(const float4*)(xp + t * 128 + nt * 16 + lg * 4);
      v[nt][0] = f.x; v[nt][1] = f.y; v[nt][2] = f.z; v[nt][3] = f.w;
    }
    float s = 0.f;
    #pragma unroll
    for (int nt = 0; nt < 8; ++nt)
      #pragma unroll
      for (int r = 0; r < 4; ++r) s += v[nt][r];
    s += __shfl_xor(s, 16); s += __shfl_xor(s, 32);
    float mu = s * 0.0078125f;
    float vv = 0.f;
    #pragma unroll
    for (int nt = 0; nt < 8; ++nt)
      #pragma unroll
      for (int r = 0; r < 4; ++r) { float d = v[nt][r] - mu; vv += d * d; }
    vv += __shfl_xor(vv, 16); vv += __shfl_xor(vv, 32);
    float rs = rsqrtf(vv * 0.0078125f + 1e-5f);
    #pragma unroll
    for (int nt = 0; nt < 8; ++nt) {
      float4 gv = *(const float4*)(g1 + nt * 16 + lg * 4);
      float4 bv = *(const float4*)(be1 + nt * 16 + lg * 4);
      *(ushort4*)(buf1 + t * LDA + nt * 16 + lg * 4) =
          pk4((v[nt][0] - mu) * rs * gv.x + bv.x, (v[nt][1] - mu) * rs * gv.y + bv.y,
              (v[nt][2] - mu) * rs * gv.z + bv.z, (v[nt][3] - mu) * rs * gv.w + bv.w);
    }
  }
  __syncthreads();   // [bar1] h complete

  // ---- QKV fused (wave w = head w): h read ONCE per mt; K,Q swapped -> packed
  bf16x8 av[4];      // V^T A-frags (k over t)
  bf16x8 bk[8];      // K A-frags (k over e, 16-padded)
  {
    bf16x8 wq[4], wk[4], wv[4];
    #pragma unroll
    for (int kk = 0; kk < 4; ++kk) {
      wq[kk] = *(const bf16x8*)(WqT + (w * 16 + l15) * 128 + kk * 32 + lg * 8);
      wk[kk] = *(const bf16x8*)(WkT + (w * 16 + l15) * 128 + kk * 32 + lg * 8);
      wv[kk] = *(const bf16x8*)(WvT + (w * 16 + l15) * 128 + kk * 32 + lg * 8);
    }
    u32 qp[8][2];     // Q packed bf16 (deferred store until bk reads done)
    f32x4 vprev = zf4;
    #pragma unroll
    for (int mt = 0; mt < 8; ++mt) {
      bf16x8 hf[4];
      #pragma unroll
      for (int kk = 0; kk < 4; ++kk)
        hf[kk] = *(const bf16x8*)(buf1 + (mt * 16 + l15) * LDA + kk * 32 + lg * 8);
      f32x4 va = zf4, ka = zf4, qa = zf4;
      #pragma unroll
      for (int kk = 0; kk < 4; ++kk) {
        va = mfma16(hf[kk], wv[kk], va);     // normal: D[t][e]
        ka = mfma16(wk[kk], hf[kk], ka);     // swapped: D[e][t] -> K[t][e] packed
        qa = mfma16(wq[kk], hf[kk], qa);
      }
      *(ushort4*)(buf2 + (mt * 16 + l15) * LDA + w * 16 + lg * 4) =
          pk4(ka[0], ka[1], ka[2], ka[3]);
      qp[mt][0] = pk2(qa[0], qa[1]);
      qp[mt][1] = pk2(qa[2], qa[3]);
      if (mt & 1) av[mt >> 1] = gatherB(vprev, va, true, 1.f, l15, lg);
      else        vprev = va;
    }
    // own-stripe K reads (within-wave RAW, compiler-ordered)
    #pragma unroll
    for (int st = 0; st < 8; ++st) {
      bk[st] = zb8;
      if (lg < 2)
        bk[st] = *(const bf16x8*)(buf2 + (st * 16 + l15) * LDA + w * 16 + lg * 8);
    }
    // Q over K stripe (within-wave WAR)
    #pragma unroll
    for (int mt = 0; mt < 8; ++mt) {
      union { u32 u[2]; ushort4 s; } uq;
      uq.u[0] = qp[mt][0]; uq.u[1] = qp[mt][1];
      *(ushort4*)(buf2 + (mt * 16 + l15) * LDA + w * 16 + lg * 4) = uq.s;
    }
  }

  // ---- attention (fully wave-private): S^T = mfma(K,Q); lane owns q-row t=l15
  #pragma unroll 1
  for (int mt = 0; mt < 8; ++mt) {
    bf16x8 aq = zb8;
    if (lg < 2)
      aq = *(const bf16x8*)(buf2 + (mt * 16 + l15) * LDA + w * 16 + lg * 8);

    f32x4 sacc[8];
    #pragma unroll
    for (int st = 0; st < 8; ++st)
      sacc[st] = (st <= mt) ? mfma16(bk[st], aq, zf4) : zf4;

    float mx = -3.0e38f;
    #pragma unroll
    for (int st = 0; st < 8; ++st) if (st <= mt) {
      #pragma unroll
      for (int rg = 0; rg < 4; ++rg) {
        float sv = sacc[st][rg] * 0.25f;
        bool ok = (st < mt) || ((lg * 4 + rg) <= l15);
        sv = ok ? sv : -1.0e30f;
        sacc[st][rg] = sv;
        mx = fmaxf(mx, sv);
      }
    }
    mx = fmaxf(mx, __shfl_xor(mx, 16));
    mx = fmaxf(mx, __shfl_xor(mx, 32));
    float sum = 0.f;
    #pragma unroll
    for (int st = 0; st < 8; ++st) if (st <= mt) {
      #pragma unroll
      for (int rg = 0; rg < 4; ++rg) {
        float e = __expf(sacc[st][rg] - mx);
        sacc[st][rg] = e;
        sum += e;
      }
    }
    sum += __shfl_xor(sum, 16);
    sum += __shfl_xor(sum, 32);
    float inv = 1.f / sum;

    f32x4 oacc = zf4;
    #pragma unroll
    for (int kk = 0; kk < 4; ++kk) if (kk <= (mt >> 1)) {
      bf16x8 fr = gatherB(sacc[2 * kk], sacc[2 * kk + 1], (2 * kk + 1) <= mt, inv, l15, lg);
      oacc = mfma16(av[kk], fr, oacc);    // D[e][t]: lane rg = O[t=l15][e=lg*4+rg]
    }
    *(ushort4*)(buf2 + (mt * 16 + l15) * LDA + w * 16 + lg * 4) =
        pk4(oacc[0], oacc[1], oacc[2], oacc[3]);
  }
  __syncthreads();   // [bar2] all O[t][e] in buf2

  // ---- Wo (swapped, 2x4 tiles) + residual: x1 kept in regs AND bf16 in buf1
  f32x4 x1r[4][2];
  {
    bf16x8 wo[2][4];
    #pragma unroll
    for (int ct = 0; ct < 2; ++ct)
      #pragma unroll
      for (int kk = 0; kk < 4; ++kk)
        wo[ct][kk] = *(const bf16x8*)(WoT + (cb + ct * 16 + l15) * 128 + kk * 32 + lg * 8);
    #pragma unroll
    for (int mt = 0; mt < 4; ++mt) {
      const int t = tr0 + mt * 16 + l15;
      bf16x8 ofr[4];
      #pragma unroll
      for (int kk = 0; kk < 4; ++kk)
        ofr[kk] = *(const bf16x8*)(buf2 + t * LDA + kk * 32 + lg * 8);
      #pragma unroll
      for (int ct = 0; ct < 2; ++ct) {
        f32x4 acc = zf4;
        #pragma unroll
        for (int kk = 0; kk < 4; ++kk)
          acc = mfma16(wo[ct][kk], ofr[kk], acc);
        float4 xv = *(const float4*)(xp + t * 128 + cb + ct * 16 + lg * 4);
        float4 bv = *(const float4*)(bo + cb + ct * 16 + lg * 4);
        x1r[mt][ct][0] = acc[0] + bv.x + xv.x;
        x1r[mt][ct][1] = acc[1] + bv.y + xv.y;
        x1r[mt][ct][2] = acc[2] + bv.z + xv.z;
        x1r[mt][ct][3] = acc[3] + bv.w + xv.w;
        *(ushort4*)(buf1 + t * LDA + cb + ct * 16 + lg * 4) =
            pk4(x1r[mt][ct][0], x1r[mt][ct][1], x1r[mt][ct][2], x1r[mt][ct][3]);
      }
    }
  }
  __syncthreads();   // [bar3] x1 bf16 complete

  // ---- LN2 (transposed-reg, in-place on buf1): wave w rows w*16..+15
  {
    const int t = w * 16 + l15;
    float v[8][4];
    #pragma unroll
    for (int nt = 0; nt < 8; ++nt) {
      ushort4 u = *(const ushort4*)(buf1 + t * LDA + nt * 16 + lg * 4);
      v[nt][0] = b2f(u.x); v[nt][1] = b2f(u.y); v[nt][2] = b2f(u.z); v[nt][3] = b2f(u.w);
    }
    float s = 0.f;
    #pragma unroll
    for (int nt = 0; nt < 8; ++nt)
      #pragma unroll
      for (int r = 0; r < 4; ++r) s += v[nt][r];
    s += __shfl_xor(s, 16); s += __shfl_xor(s, 32);
    float mu = s * 0.0078125f;
    float vv = 0.f;
    #pragma unroll
    for (int nt = 0; nt < 8; ++nt)
      #pragma unroll
      for (int r = 0; r < 4; ++r) { float d = v[nt][r] - mu; vv += d * d; }
    vv += __shfl_xor(vv, 16); vv += __shfl_xor(vv, 32);
    float rs = rsqrtf(vv * 0.0078125f + 1e-5f);
    #pragma unroll
    for (int nt = 0; nt < 8; ++nt) {
      float4 gv = *(const float4*)(g2 + nt * 16 + lg * 4);
      float4 bv = *(const float4*)(be2 + nt * 16 + lg * 4);
      *(ushort4*)(buf1 + t * LDA + nt * 16 + lg * 4) =
          pk4((v[nt][0] - mu) * rs * gv.x + bv.x, (v[nt][1] - mu) * rs * gv.y + bv.y,
              (v[nt][2] - mu) * rs * gv.z + bv.z, (v[nt][3] - mu) * rs * gv.w + bv.w);
    }
  }
  __syncthreads();   // [bar4] h2 complete

  // ---- FFN (swapped, 2x4 tiles), relu bounce through buf2 per cc
  {
    f32x4 oacc[4][2];
    #pragma unroll
    for (int mt = 0; mt < 4; ++mt)
      #pragma unroll
      for (int ct = 0; ct < 2; ++ct) oacc[mt][ct] = zf4;

    #pragma unroll 1
    for (int cc = 0; cc < 4; ++cc) {
      bf16x8 w1f[2][4];
      #pragma unroll
      for (int ct = 0; ct < 2; ++ct)
        #pragma unroll
        for (int kk = 0; kk < 4; ++kk)
          w1f[ct][kk] = *(const bf16x8*)(W1T + (cc * 128 + cb + ct * 16 + l15) * 128 + kk * 32 + lg * 8);
      #pragma unroll
      for (int mt = 0; mt < 4; ++mt) {
        const int t = tr0 + mt * 16 + l15;
        bf16x8 h2f[4];
        #pragma unroll
        for (int kk = 0; kk < 4; ++kk)
          h2f[kk] = *(const bf16x8*)(buf1 + t * LDA + kk * 32 + lg * 8);
        #pragma unroll
        for (int ct = 0; ct < 2; ++ct) {
          f32x4 fa = zf4;
          #pragma unroll
          for (int kk = 0; kk < 4; ++kk)
            fa = mfma16(w1f[ct][kk], h2f[kk], fa);
          float4 bv = *(const float4*)(b1 + cc * 128 + cb + ct * 16 + lg * 4);
          *(ushort4*)(buf2 + t * LDA + cb + ct * 16 + lg * 4) =
              pk4(fmaxf(fa[0] + bv.x, 0.f), fmaxf(fa[1] + bv.y, 0.f),
                  fmaxf(fa[2] + bv.z, 0.f), fmaxf(fa[3] + bv.w, 0.f));
        }
      }
      __syncthreads();   // relu chunk complete

      bf16x8 w2f[2][4];
      #pragma unroll
      for (int ct = 0; ct < 2; ++ct)
        #pragma unroll
        for (int kk = 0; kk < 4; ++kk)
          w2f[ct][kk] = *(const bf16x8*)(W2T2 + (cb + ct * 16 + l15) * 512 + cc * 128 + kk * 32 + lg * 8);
      #pragma unroll
      for (int mt = 0; mt < 4; ++mt) {
        bf16x8 rf[4];
        #pragma unroll
        for (int kk = 0; kk < 4; ++kk)
          rf[kk] = *(const bf16x8*)(buf2 + (tr0 + mt * 16 + l15) * LDA + kk * 32 + lg * 8);
        #pragma unroll
        for (int ct = 0; ct < 2; ++ct)
          #pragma unroll
          for (int kk = 0; kk < 4; ++kk)
            oacc[mt][ct] = mfma16(w2f[ct][kk], rf[kk], oacc[mt][ct]);
      }
      if (cc < 3) __syncthreads();   // relu reads done before overwrite
    }

    // ---- epilogue: out = oacc + b2 + x1 (regs), float4 stores
    #pragma unroll
    for (int mt = 0; mt < 4; ++mt) {
      const int t = tr0 + mt * 16 + l15;
      #pragma unroll
      for (int ct = 0; ct < 2; ++ct) {
        float4 bv = *(const float4*)(b2 + cb + ct * 16 + lg * 4);
        float4 st;
        st.x = oacc[mt][ct][0] + bv.x + x1r[mt][ct][0];
        st.y = oacc[mt][ct][1] + bv.y + x1r[mt][ct][1];
        st.z = oacc[mt][ct][2] + bv.z + x1r[mt][ct][2];
        st.w = oacc[mt][ct][3] + bv.w + x1r[mt][ct][3];
        *(float4*)(op + t * 128 + cb + ct * 16 + lg * 4) = st;
      }
    }
  }
}

extern "C" void kernel_launch(void* const* d_in, const int* in_sizes, int n_in,
                              void* d_out, int out_size, void* d_ws, size_t ws_size,
                              hipStream_t stream) {
  const float* x   = (const float*)d_in[0];
  const float* Wq  = (const float*)d_in[1];
  const float* Wk  = (const float*)d_in[2];
  const float* Wv  = (const float*)d_in[3];
  const float* Wo  = (const float*)d_in[4];
  const float* bo  = (const float*)d_in[5];
  const float* W1  = (const float*)d_in[6];
  const float* b1  = (const float*)d_in[7];
  const float* W2  = (const float*)d_in[8];
  const float* b2  = (const float*)d_in[9];
  const float* g1  = (const float*)d_in[10];
  const float* be1 = (const float*)d_in[11];
  const float* g2  = (const float*)d_in[12];
  const float* be2 = (const float*)d_in[13];
  u16* wts = (u16*)d_ws;

  prep_kernel<<<768, 256, 0, stream>>>(Wq, Wk, Wv, Wo, W1, W2, wts);

  const int smem_bytes = 2 * 128 * LDA * 2;  // 69632 -> 2 blocks/CU
  hipFuncSetAttribute(reinterpret_cast<const void*>(tblock_kernel),
                      hipFuncAttributeMaxDynamicSharedMemorySize, smem_bytes);
  tblock_kernel<<<1024, 512, smem_bytes, stream>>>(x, wts, bo, b1, b2, g1, be1, g2,
                                                   be2, (float*)d_out);
}

// Round 6
// 154.246 us; speedup vs baseline: 1.0738x; 1.0738x over previous
//
#include <hip/hip_runtime.h>
#include <hip/hip_bf16.h>

typedef unsigned short u16;
typedef unsigned int u32;
typedef __bf16 bf16x8 __attribute__((ext_vector_type(8)));
typedef float f32x4 __attribute__((ext_vector_type(4)));

#define LDA 136   // 128+8 bf16 pad: row stride 272B = 16B-aligned, non-pow2 banks

__device__ __forceinline__ u16 f2b(float f) {
  __bf16 b = (__bf16)f;
  return __builtin_bit_cast(u16, b);
}
__device__ __forceinline__ float b2f(u16 h) {
  u32 u = ((u32)h) << 16;
  return __builtin_bit_cast(float, u);
}
__device__ __forceinline__ u32 pk2(float lo, float hi) {
  return (u32)f2b(lo) | ((u32)f2b(hi) << 16);
}
__device__ __forceinline__ bf16x8 zero8() {
  union { int4 i; bf16x8 v; } u;
  u.i = make_int4(0, 0, 0, 0);
  return u.v;
}
__device__ __forceinline__ f32x4 mfma16(bf16x8 a, bf16x8 b, f32x4 c) {
  return __builtin_amdgcn_mfma_f32_16x16x32_bf16(a, b, c, 0, 0, 0);
}
__device__ __forceinline__ ushort4 pk4(float a, float b, float c, float d) {
  ushort4 r; r.x = f2b(a); r.y = f2b(b); r.z = f2b(c); r.w = f2b(d);
  return r;
}

// Transpose C-layout frag pair {ve=tile 2kk, vo=tile 2kk+1} (row-index -> k):
// output lane(l15,lg) element j = M[row=kk*32+lg*8+j][col=l15].
// Verified R3/R4/R5 (P^T gather and av build passed absmax).
__device__ __forceinline__ bf16x8 gatherB(const f32x4& ve, const f32x4& vo,
                                          bool odd_valid, float scale,
                                          int l15, int lg) {
  u32 pe0 = pk2(ve[0] * scale, ve[1] * scale);
  u32 pe1 = pk2(ve[2] * scale, ve[3] * scale);
  u32 po0 = 0, po1 = 0;
  if (odd_valid) {
    po0 = pk2(vo[0] * scale, vo[1] * scale);
    po1 = pk2(vo[2] * scale, vo[3] * scale);
  }
  int s0 = ((lg & 1) * 2) * 16 + l15;
  u32 a0 = __shfl(pe0, s0),      a1 = __shfl(pe1, s0);
  u32 a2 = __shfl(pe0, s0 + 16), a3 = __shfl(pe1, s0 + 16);
  u32 b0 = __shfl(po0, s0),      b1 = __shfl(po1, s0);
  u32 b2 = __shfl(po0, s0 + 16), b3 = __shfl(po1, s0 + 16);
  union { u32 u[4]; bf16x8 v; } fr;
  bool lo = (lg < 2);
  fr.u[0] = lo ? a0 : b0; fr.u[1] = lo ? a1 : b1;
  fr.u[2] = lo ? a2 : b2; fr.u[3] = lo ? a3 : b3;
  return fr.v;
}

// ---------------- weight prep ----------------
// ws (u16): WqT[128][128]@0 (WqT[h*16+e][d]=Wq[h][d][e]), WkT@16384, WvT@32768,
//           WoT@49152 (WoT[n][k]=Wo[k][n]), W1T[512][128]@65536 (W1T[n][k]=W1[k][n]),
//           W2T2[128][512]@131072 (W2T2[c][n]=W2[n][c])
__global__ void prep_kernel(const float* __restrict__ Wq, const float* __restrict__ Wk,
                            const float* __restrict__ Wv, const float* __restrict__ Wo,
                            const float* __restrict__ W1, const float* __restrict__ W2,
                            u16* __restrict__ o) {
  int i = blockIdx.x * 256 + threadIdx.x;
  if (i >= 196608) return;
  float v;
  if (i < 49152) {
    int which = i >> 14, j = i & 16383;
    int n = j >> 7, k = j & 127;
    const float* W = (which == 0) ? Wq : (which == 1) ? Wk : Wv;
    v = W[((n >> 4) * 128 + k) * 16 + (n & 15)];
  } else if (i < 65536) {
    int j = i - 49152;
    v = Wo[(j & 127) * 128 + (j >> 7)];
  } else if (i < 131072) {
    int j = i - 65536;
    v = W1[(j & 127) * 512 + (j >> 7)];
  } else {
    int j = i - 131072;
    int c = j >> 9, n = j & 511;
    v = W2[n * 128 + c];
  }
  o[i] = f2b(v);
}

// ---------------- fused transformer block ----------------
// 8 waves, 2 LDS buffers (69.6 KB -> 2 blocks/CU). Weights ride the MFMA A-slot
// (swapped orientation) so activation stores are packed ushort4 and residual
// global I/O is float4. Attention fully wave-private (wave w = head w).
// Residual x1 lives in the FFN accumulator (oacc init = x1 + b2): zero extra
// registers, fp32-exact, no global round-trip.
__global__ void __launch_bounds__(512, 4)
tblock_kernel(const float* __restrict__ xg, const u16* __restrict__ wts,
              const float* __restrict__ bo, const float* __restrict__ b1,
              const float* __restrict__ b2, const float* __restrict__ g1,
              const float* __restrict__ be1, const float* __restrict__ g2,
              const float* __restrict__ be2, float* __restrict__ out) {
  extern __shared__ u16 sm[];
  u16* buf1 = sm;                // h -> x1(bf16) -> h2(LN2 in-place)
  u16* buf2 = sm + 128 * LDA;    // K -> Q -> O(in-place) -> relu chunks

  const int tid  = threadIdx.x;
  const int w    = tid >> 6;
  const int lane = tid & 63;
  const int l15  = lane & 15;
  const int lg   = lane >> 4;
  const int mr   = w >> 2;           // Wo/FFN: row half 0/1 (64 rows)
  const int nc   = w & 3;            // Wo/FFN: col group (32 cols)
  const int tr0  = mr * 64;
  const int cb   = nc * 32;

  const u16* WqT  = wts;
  const u16* WkT  = wts + 16384;
  const u16* WvT  = wts + 32768;
  const u16* WoT  = wts + 49152;
  const u16* W1T  = wts + 65536;
  const u16* W2T2 = wts + 131072;

  const float* xp = xg + (size_t)blockIdx.x * 16384;
  float*       op = out + (size_t)blockIdx.x * 16384;

  const f32x4 zf4 = {0.f, 0.f, 0.f, 0.f};
  const bf16x8 zb8 = zero8();

  // ---- LN1 (transposed-reg): wave w owns rows w*16..+15; float4 x loads
  {
    const int t = w * 16 + l15;
    float v[8][4];
    #pragma unroll
    for (int nt = 0; nt < 8; ++nt) {
      float4 f = *(const float4*)(xp + t * 128 + nt * 16 + lg * 4);
      v[nt][0] = f.x; v[nt][1] = f.y; v[nt][2] = f.z; v[nt][3] = f.w;
    }
    float s = 0.f;
    #pragma unroll
    for (int nt = 0; nt < 8; ++nt)
      #pragma unroll
      for (int r = 0; r < 4; ++r) s += v[nt][r];
    s += __shfl_xor(s, 16); s += __shfl_xor(s, 32);
    float mu = s * 0.0078125f;
    float vv = 0.f;
    #pragma unroll
    for (int nt = 0; nt < 8; ++nt)
      #pragma unroll
      for (int r = 0; r < 4; ++r) { float d = v[nt][r] - mu; vv += d * d; }
    vv += __shfl_xor(vv, 16); vv += __shfl_xor(vv, 32);
    float rs = rsqrtf(vv * 0.0078125f + 1e-5f);
    #pragma unroll
    for (int nt = 0; nt < 8; ++nt) {
      float4 gv = *(const float4*)(g1 + nt * 16 + lg * 4);
      float4 bv = *(const float4*)(be1 + nt * 16 + lg * 4);
      *(ushort4*)(buf1 + t * LDA + nt * 16 + lg * 4) =
          pk4((v[nt][0] - mu) * rs * gv.x + bv.x, (v[nt][1] - mu) * rs * gv.y + bv.y,
              (v[nt][2] - mu) * rs * gv.z + bv.z, (v[nt][3] - mu) * rs * gv.w + bv.w);
    }
  }
  __syncthreads();   // [bar1] h complete

  // ---- V pass (wave w = head w): av[4] = V^T A-frags via gatherB, no LDS
  bf16x8 av[4];
  {
    bf16x8 wv[4];
    #pragma unroll
    for (int kk = 0; kk < 4; ++kk)
      wv[kk] = *(const bf16x8*)(WvT + (w * 16 + l15) * 128 + kk * 32 + lg * 8);
    f32x4 vprev = zf4;
    #pragma unroll
    for (int mt = 0; mt < 8; ++mt) {
      f32x4 va = zf4;
      #pragma unroll
      for (int kk = 0; kk < 4; ++kk)
        va = mfma16(*(const bf16x8*)(buf1 + (mt * 16 + l15) * LDA + kk * 32 + lg * 8),
                    wv[kk], va);          // normal: D[t][e]
      if (mt & 1) av[mt >> 1] = gatherB(vprev, va, true, 1.f, l15, lg);
      else        vprev = va;
    }
  }

  // ---- K+Q fused pass (swapped -> packed col-stripe stores), bk into regs
  bf16x8 bk[8];
  {
    bf16x8 wk[4], wq[4];
    #pragma unroll
    for (int kk = 0; kk < 4; ++kk) {
      wk[kk] = *(const bf16x8*)(WkT + (w * 16 + l15) * 128 + kk * 32 + lg * 8);
      wq[kk] = *(const bf16x8*)(WqT + (w * 16 + l15) * 128 + kk * 32 + lg * 8);
    }
    u32 qp[8][2];     // Q packed (deferred store until bk reads done)
    #pragma unroll
    for (int mt = 0; mt < 8; ++mt) {
      bf16x8 hf[4];
      #pragma unroll
      for (int kk = 0; kk < 4; ++kk)
        hf[kk] = *(const bf16x8*)(buf1 + (mt * 16 + l15) * LDA + kk * 32 + lg * 8);
      f32x4 ka = zf4, qa = zf4;
      #pragma unroll
      for (int kk = 0; kk < 4; ++kk) {
        ka = mfma16(wk[kk], hf[kk], ka);   // swapped: D[e][t] -> K[t][e] packed
        qa = mfma16(wq[kk], hf[kk], qa);
      }
      *(ushort4*)(buf2 + (mt * 16 + l15) * LDA + w * 16 + lg * 4) =
          pk4(ka[0], ka[1], ka[2], ka[3]);
      qp[mt][0] = pk2(qa[0], qa[1]);
      qp[mt][1] = pk2(qa[2], qa[3]);
    }
    // own-stripe K reads (within-wave RAW, compiler-ordered)
    #pragma unroll
    for (int st = 0; st < 8; ++st) {
      bk[st] = zb8;
      if (lg < 2)
        bk[st] = *(const bf16x8*)(buf2 + (st * 16 + l15) * LDA + w * 16 + lg * 8);
    }
    // Q over K stripe (within-wave WAR)
    #pragma unroll
    for (int mt = 0; mt < 8; ++mt) {
      union { u32 u[2]; ushort4 s; } uq;
      uq.u[0] = qp[mt][0]; uq.u[1] = qp[mt][1];
      *(ushort4*)(buf2 + (mt * 16 + l15) * LDA + w * 16 + lg * 4) = uq.s;
    }
  }

  // ---- attention (fully wave-private): S^T = mfma(K,Q); lane owns q-row t=l15
  #pragma unroll 1
  for (int mt = 0; mt < 8; ++mt) {
    bf16x8 aq = zb8;
    if (lg < 2)
      aq = *(const bf16x8*)(buf2 + (mt * 16 + l15) * LDA + w * 16 + lg * 8);

    f32x4 sacc[8];
    #pragma unroll
    for (int st = 0; st < 8; ++st)
      sacc[st] = (st <= mt) ? mfma16(bk[st], aq, zf4) : zf4;

    float mx = -3.0e38f;
    #pragma unroll
    for (int st = 0; st < 8; ++st) if (st <= mt) {
      #pragma unroll
      for (int rg = 0; rg < 4; ++rg) {
        float sv = sacc[st][rg] * 0.25f;
        bool ok = (st < mt) || ((lg * 4 + rg) <= l15);
        sv = ok ? sv : -1.0e30f;
        sacc[st][rg] = sv;
        mx = fmaxf(mx, sv);
      }
    }
    mx = fmaxf(mx, __shfl_xor(mx, 16));
    mx = fmaxf(mx, __shfl_xor(mx, 32));
    float sum = 0.f;
    #pragma unroll
    for (int st = 0; st < 8; ++st) if (st <= mt) {
      #pragma unroll
      for (int rg = 0; rg < 4; ++rg) {
        float e = __expf(sacc[st][rg] - mx);
        sacc[st][rg] = e;
        sum += e;
      }
    }
    sum += __shfl_xor(sum, 16);
    sum += __shfl_xor(sum, 32);
    float inv = 1.f / sum;

    f32x4 oa = zf4;
    #pragma unroll
    for (int kk = 0; kk < 4; ++kk) if (kk <= (mt >> 1)) {
      bf16x8 fr = gatherB(sacc[2 * kk], sacc[2 * kk + 1], (2 * kk + 1) <= mt, inv, l15, lg);
      oa = mfma16(av[kk], fr, oa);      // D[e][t]: lane rg = O[t=l15][e=lg*4+rg]
    }
    *(ushort4*)(buf2 + (mt * 16 + l15) * LDA + w * 16 + lg * 4) =
        pk4(oa[0], oa[1], oa[2], oa[3]);
  }
  __syncthreads();   // [bar2] all O[t][e] in buf2; all h reads done

  // ---- Wo (swapped, 2x4 tiles) + residual:
  //      oacc init = x1 + b2 (residual rides the FFN accumulator, fp32-exact);
  //      x1 bf16 -> buf1 (over dead h) for LN2.
  f32x4 oacc[4][2];
  {
    bf16x8 wo[2][4];
    #pragma unroll
    for (int ct = 0; ct < 2; ++ct)
      #pragma unroll
      for (int kk = 0; kk < 4; ++kk)
        wo[ct][kk] = *(const bf16x8*)(WoT + (cb + ct * 16 + l15) * 128 + kk * 32 + lg * 8);
    #pragma unroll
    for (int mt = 0; mt < 4; ++mt) {
      const int t = tr0 + mt * 16 + l15;
      bf16x8 ofr[4];
      #pragma unroll
      for (int kk = 0; kk < 4; ++kk)
        ofr[kk] = *(const bf16x8*)(buf2 + t * LDA + kk * 32 + lg * 8);
      #pragma unroll
      for (int ct = 0; ct < 2; ++ct) {
        f32x4 acc = zf4;
        #pragma unroll
        for (int kk = 0; kk < 4; ++kk)
          acc = mfma16(wo[ct][kk], ofr[kk], acc);
        float4 xv  = *(const float4*)(xp + t * 128 + cb + ct * 16 + lg * 4);
        float4 bov = *(const float4*)(bo + cb + ct * 16 + lg * 4);
        float4 b2v = *(const float4*)(b2 + cb + ct * 16 + lg * 4);
        float x10 = acc[0] + bov.x + xv.x;
        float x11 = acc[1] + bov.y + xv.y;
        float x12 = acc[2] + bov.z + xv.z;
        float x13 = acc[3] + bov.w + xv.w;
        oacc[mt][ct][0] = x10 + b2v.x;
        oacc[mt][ct][1] = x11 + b2v.y;
        oacc[mt][ct][2] = x12 + b2v.z;
        oacc[mt][ct][3] = x13 + b2v.w;
        *(ushort4*)(buf1 + t * LDA + cb + ct * 16 + lg * 4) = pk4(x10, x11, x12, x13);
      }
    }
  }
  __syncthreads();   // [bar3] x1(bf16) complete; O reads done

  // ---- LN2 (transposed-reg, in-place on buf1): wave w rows w*16..+15
  {
    const int t = w * 16 + l15;
    float v[8][4];
    #pragma unroll
    for (int nt = 0; nt < 8; ++nt) {
      ushort4 u = *(const ushort4*)(buf1 + t * LDA + nt * 16 + lg * 4);
      v[nt][0] = b2f(u.x); v[nt][1] = b2f(u.y); v[nt][2] = b2f(u.z); v[nt][3] = b2f(u.w);
    }
    float s = 0.f;
    #pragma unroll
    for (int nt = 0; nt < 8; ++nt)
      #pragma unroll
      for (int r = 0; r < 4; ++r) s += v[nt][r];
    s += __shfl_xor(s, 16); s += __shfl_xor(s, 32);
    float mu = s * 0.0078125f;
    float vv = 0.f;
    #pragma unroll
    for (int nt = 0; nt < 8; ++nt)
      #pragma unroll
      for (int r = 0; r < 4; ++r) { float d = v[nt][r] - mu; vv += d * d; }
    vv += __shfl_xor(vv, 16); vv += __shfl_xor(vv, 32);
    float rs = rsqrtf(vv * 0.0078125f + 1e-5f);
    #pragma unroll
    for (int nt = 0; nt < 8; ++nt) {
      float4 gv = *(const float4*)(g2 + nt * 16 + lg * 4);
      float4 bv = *(const float4*)(be2 + nt * 16 + lg * 4);
      *(ushort4*)(buf1 + t * LDA + nt * 16 + lg * 4) =
          pk4((v[nt][0] - mu) * rs * gv.x + bv.x, (v[nt][1] - mu) * rs * gv.y + bv.y,
              (v[nt][2] - mu) * rs * gv.z + bv.z, (v[nt][3] - mu) * rs * gv.w + bv.w);
    }
  }
  __syncthreads();   // [bar4] h2 complete

  // ---- FFN (swapped, 2x4 tiles), relu bounce through buf2 per cc;
  //      oacc already carries x1 + b2.
  {
    #pragma unroll 1
    for (int cc = 0; cc < 4; ++cc) {
      bf16x8 w1f[2][4];
      #pragma unroll
      for (int ct = 0; ct < 2; ++ct)
        #pragma unroll
        for (int kk = 0; kk < 4; ++kk)
          w1f[ct][kk] = *(const bf16x8*)(W1T + (cc * 128 + cb + ct * 16 + l15) * 128 + kk * 32 + lg * 8);
      #pragma unroll
      for (int mt = 0; mt < 4; ++mt) {
        const int t = tr0 + mt * 16 + l15;
        bf16x8 h2f[4];
        #pragma unroll
        for (int kk = 0; kk < 4; ++kk)
          h2f[kk] = *(const bf16x8*)(buf1 + t * LDA + kk * 32 + lg * 8);
        #pragma unroll
        for (int ct = 0; ct < 2; ++ct) {
          f32x4 fa = zf4;
          #pragma unroll
          for (int kk = 0; kk < 4; ++kk)
            fa = mfma16(w1f[ct][kk], h2f[kk], fa);
          float4 bv = *(const float4*)(b1 + cc * 128 + cb + ct * 16 + lg * 4);
          *(ushort4*)(buf2 + t * LDA + cb + ct * 16 + lg * 4) =
              pk4(fmaxf(fa[0] + bv.x, 0.f), fmaxf(fa[1] + bv.y, 0.f),
                  fmaxf(fa[2] + bv.z, 0.f), fmaxf(fa[3] + bv.w, 0.f));
        }
      }
      __syncthreads();   // relu chunk complete

      bf16x8 w2f[2][4];
      #pragma unroll
      for (int ct = 0; ct < 2; ++ct)
        #pragma unroll
        for (int kk = 0; kk < 4; ++kk)
          w2f[ct][kk] = *(const bf16x8*)(W2T2 + (cb + ct * 16 + l15) * 512 + cc * 128 + kk * 32 + lg * 8);
      #pragma unroll
      for (int mt = 0; mt < 4; ++mt) {
        bf16x8 rf[4];
        #pragma unroll
        for (int kk = 0; kk < 4; ++kk)
          rf[kk] = *(const bf16x8*)(buf2 + (tr0 + mt * 16 + l15) * LDA + kk * 32 + lg * 8);
        #pragma unroll
        for (int ct = 0; ct < 2; ++ct)
          #pragma unroll
          for (int kk = 0; kk < 4; ++kk)
            oacc[mt][ct] = mfma16(w2f[ct][kk], rf[kk], oacc[mt][ct]);
      }
      if (cc < 3) __syncthreads();   // relu reads done before overwrite
    }

    // ---- epilogue: out = oacc (x1 + b2 + ffn), float4 stores
    #pragma unroll
    for (int mt = 0; mt < 4; ++mt) {
      const int t = tr0 + mt * 16 + l15;
      #pragma unroll
      for (int ct = 0; ct < 2; ++ct) {
        float4 st;
        st.x = oacc[mt][ct][0];
        st.y = oacc[mt][ct][1];
        st.z = oacc[mt][ct][2];
        st.w = oacc[mt][ct][3];
        *(float4*)(op + t * 128 + cb + ct * 16 + lg * 4) = st;
      }
    }
  }
}

extern "C" void kernel_launch(void* const* d_in, const int* in_sizes, int n_in,
                              void* d_out, int out_size, void* d_ws, size_t ws_size,
                              hipStream_t stream) {
  const float* x   = (const float*)d_in[0];
  const float* Wq  = (const float*)d_in[1];
  const float* Wk  = (const float*)d_in[2];
  const float* Wv  = (const float*)d_in[3];
  const float* Wo  = (const float*)d_in[4];
  const float* bo  = (const float*)d_in[5];
  const float* W1  = (const float*)d_in[6];
  const float* b1  = (const float*)d_in[7];
  const float* W2  = (const float*)d_in[8];
  const float* b2  = (const float*)d_in[9];
  const float* g1  = (const float*)d_in[10];
  const float* be1 = (const float*)d_in[11];
  const float* g2  = (const float*)d_in[12];
  const float* be2 = (const float*)d_in[13];
  u16* wts = (u16*)d_ws;

  prep_kernel<<<768, 256, 0, stream>>>(Wq, Wk, Wv, Wo, W1, W2, wts);

  const int smem_bytes = 2 * 128 * LDA * 2;  // 69632 -> 2 blocks/CU
  hipFuncSetAttribute(reinterpret_cast<const void*>(tblock_kernel),
                      hipFuncAttributeMaxDynamicSharedMemorySize, smem_bytes);
  tblock_kernel<<<1024, 512, smem_bytes, stream>>>(x, wts, bo, b1, b2, g1, be1, g2,
                                                   be2, (float*)d_out);
}